// Round 6
// baseline (443.489 us; speedup 1.0000x reference)
//
#include <hip/hip_runtime.h>
#include <hip/hip_bf16.h>

typedef unsigned int u32;
typedef unsigned short u16;

#define DEVINL __device__ __forceinline__

constexpr int Nn  = 25000;
constexpr int Ee  = 100000;
constexpr int NCc = 8000;
constexpr int Aa  = 50000;
constexpr int ECc = 24000;
constexpr int TCOLS = 1088;   // 34 rows * 32 cols: k=0..31 -> T, k=32 -> x@b2, k=33 -> x@rootw+rootb
constexpr int WPSZ  = TCOLS*32;   // one packed weight set

typedef float f32x4 __attribute__((ext_vector_type(4)));
typedef short s16x8 __attribute__((ext_vector_type(8)));

DEVINL float b2f(u16 u){ union{u32 i;float f;}v; v.i = ((u32)u)<<16; return v.f; }
DEVINL float bfl(u32 u){ union{u32 i;float f;}v; v.i = u<<16; return v.f; }
DEVINL float bfh(u32 u){ union{u32 i;float f;}v; v.i = u & 0xffff0000u; return v.f; }
DEVINL u16 f2b(float f){ union{float f;u32 i;}v; v.f=f; u32 i=v.i;
  return (u16)((i + 0x7fffu + ((i>>16)&1u)) >> 16); }
DEVINL float ldw(const void* p, long i, int f){
  return f ? ((const float*)p)[i] : b2f(((const u16*)p)[i]);
}

// ---------- dtype detection + flag (fused via last-block-done) ----------
__global__ __launch_bounds__(256) void k_detect(const u16* __restrict__ p, int n,
                        u32* __restrict__ maxbits, int* __restrict__ zcnt,
                        int* __restrict__ done, int* __restrict__ flag){
  int i0 = blockIdx.x*256 + threadIdx.x;
  float lm = 0.f; int lz = 0;
  for (int i = i0; i < n; i += gridDim.x*256){
    u16 v = p[i];
    if (v == 0) lz++;
    lm = fmaxf(lm, fabsf(b2f(v)));
  }
  #pragma unroll
  for (int off = 32; off; off >>= 1){
    lm = fmaxf(lm, __shfl_down(lm, off));
    lz += __shfl_down(lz, off);
  }
  if ((threadIdx.x & 63) == 0){
    atomicMax(maxbits, __float_as_uint(lm));
    atomicAdd(zcnt, lz);
  }
  __syncthreads();
  if (threadIdx.x == 0){
    __threadfence();
    if (atomicAdd(done, 1) == gridDim.x - 1){
      float m = __uint_as_float(*maxbits);
      *flag = (m > 1e6f || *zcnt > n/4) ? 1 : 0;   // 1 => inputs are f32
    }
  }
}

// ---------- convert both feature tensors in one grid ----------
__global__ __launch_bounds__(256) void k_conv_all(const void* __restrict__ xin, const void* __restrict__ cin,
                         float* __restrict__ xA, float* __restrict__ cA, const int* __restrict__ flag){
  int i = blockIdx.x*256 + threadIdx.x;
  int f = *flag;
  if (i < Nn*32) xA[i] = ldw(xin, i, f);
  else { i -= Nn*32; if (i < NCc*32) cA[i] = ldw(cin, i, f); }
}

// ---------- all degree/count histograms in one kernel ----------
__global__ __launch_bounds__(256) void k_count_all(const int* __restrict__ ei, const int* __restrict__ cei,
                          const int* __restrict__ n2c,
                          int* __restrict__ deg_nd, int* __restrict__ deg_ce,
                          int* __restrict__ deg_n2c, int* __restrict__ deg_c2n,
                          int* __restrict__ cnt_sn, int* __restrict__ cnt_sc){
  int i = blockIdx.x*256 + threadIdx.x;
  if (i < Ee)                             atomicAdd(&deg_nd[ei[Ee + i]], 1);
  else if ((i -= Ee) < ECc)               atomicAdd(&deg_ce[cei[ECc + i]], 1);
  else if ((i -= ECc) < Aa)               atomicAdd(&deg_n2c[n2c[Aa + i]], 1);
  else if ((i -= Aa) < Aa)                atomicAdd(&deg_c2n[n2c[i]], 1);
  else if ((i -= Aa) < Ee)                atomicAdd(&cnt_sn[ei[i]], 1);
  else if ((i -= Ee) < ECc)               atomicAdd(&cnt_sc[cei[i]], 1);
}

// ---------- single-kernel exclusive scan (1024 threads, wave-scan) ----------
__global__ __launch_bounds__(1024) void k_scan_all(const int* __restrict__ cnt_n, const int* __restrict__ cnt_c,
                          int* __restrict__ offs_n, int* __restrict__ offs_c){
  __shared__ int wsum[16], wpre[16];
  __shared__ int carry_s;
  int tid = threadIdx.x, lane = tid & 63, w = tid >> 6;
  for (int pass = 0; pass < 2; pass++){
    const int* cnt = pass ? cnt_c : cnt_n;
    int* offs = pass ? offs_c : offs_n;
    int M = pass ? NCc : Nn;
    if (tid == 0) carry_s = 0;
    __syncthreads();
    for (int base = 0; base < M; base += 1024){
      int i = base + tid;
      int v = (i < M) ? cnt[i] : 0;
      int x = v;
      #pragma unroll
      for (int d = 1; d < 64; d <<= 1){ int t = __shfl_up(x, d); if (lane >= d) x += t; }
      if (lane == 63) wsum[w] = x;
      __syncthreads();
      if (w == 0){
        int t = (lane < 16) ? wsum[lane] : 0;
        int y = t;
        #pragma unroll
        for (int d = 1; d < 16; d <<= 1){ int t2 = __shfl_up(y, d); if (lane >= d) y += t2; }
        if (lane < 16) wpre[lane] = y - t;
      }
      __syncthreads();
      if (i < M) offs[i] = carry_s + wpre[w] + x - v;
      int tot = wpre[15] + wsum[15];
      __syncthreads();
      if (tid == 0) carry_s += tot;
      __syncthreads();
    }
  }
}

__global__ __launch_bounds__(256) void k_place(const int* __restrict__ ei, const int* __restrict__ cei,
                      const int* __restrict__ offs_n, const int* __restrict__ offs_c,
                      int* __restrict__ cur_n, int* __restrict__ cur_c,
                      int* __restrict__ perm_n, int* __restrict__ perm_c){
  int i = blockIdx.x*256 + threadIdx.x;
  if (i < Ee){
    int s = ei[i];
    perm_n[offs_n[s] + atomicAdd(&cur_n[s], 1)] = i;
  } else if ((i -= Ee) < ECc){
    int s = cei[i];
    perm_c[offs_c[s] + atomicAdd(&cur_c[s], 1)] = i;
  }
}

// ---------- pack all 4 weight sets at once: set = l*2 + isClique ----------
__global__ __launch_bounds__(256) void k_wpack_all(const void* __restrict__ nn2w, const void* __restrict__ nn2b,
                          const void* __restrict__ rootw,
                          const void* __restrict__ cnn2w, const void* __restrict__ cnn2b,
                          const void* __restrict__ crootw,
                          const int* __restrict__ flag, u16* __restrict__ Wp4){
  int i = blockIdx.x*256 + threadIdx.x;
  if (i >= 4*WPSZ) return;
  int set = i / WPSZ, j = i - set*WPSZ;
  int l = set >> 1, isC = set & 1;
  const void* W2 = isC ? cnn2w : nn2w;
  const void* B2 = isC ? cnn2b : nn2b;
  const void* RW = isC ? crootw : rootw;
  int f = *flag;
  int col = j >> 5, ii = j & 31;
  float v;
  if (col < 1024)      v = ldw(W2, (long)l*32768 + ((col>>5)<<10) + (ii<<5) + (col&31), f);
  else if (col < 1056) v = ldw(B2, (long)l*1024 + (ii<<5) + (col-1024), f);
  else                 v = ldw(RW, (long)l*1024 + (ii<<5) + (col-1056), f);
  Wp4[i] = f2b(v);
}

// ---------- MFMA feat gemm, optional folded residual-mean on the input ----------
__global__ __launch_bounds__(256) void k_feat_gemm_mfma(const float* __restrict__ base,
                            const float* __restrict__ addagg, const int* __restrict__ adddeg, int M,
                            const u16* __restrict__ Wp,
                            const void* __restrict__ rb, long rboff, const int* __restrict__ flag,
                            u16* __restrict__ T){
  int wave = threadIdx.x >> 6;
  int lane = threadIdx.x & 63;
  int quad = lane >> 4, lm = lane & 15;
  int ntile = blockIdx.x*64 + wave*16;
  int n = ntile + lm;
  int nc = n < M ? n : M-1;
  int f = *flag;
  const float* bp = base + (size_t)nc*32 + quad*8;
  s16x8 bfrag;
  if (addagg){
    int dg = adddeg[nc];
    float d = (float)(dg > 1 ? dg : 1);
    const float* ap = addagg + (size_t)nc*32 + quad*8;
    #pragma unroll
    for (int j = 0; j < 8; j++) bfrag[j] = (short)f2b(bp[j] + ap[j]/d);
  } else {
    #pragma unroll
    for (int j = 0; j < 8; j++) bfrag[j] = (short)f2b(bp[j]);
  }
  int t0 = blockIdx.y * 17;
  for (int ti = 0; ti < 17; ti++){
    int colbase = (t0 + ti) * 16;
    s16x8 afrag = *(const s16x8*)(Wp + (size_t)(colbase + lm)*32 + quad*8);
    f32x4 acc = {0.f, 0.f, 0.f, 0.f};
    acc = __builtin_amdgcn_mfma_f32_16x16x32_bf16(afrag, bfrag, acc, 0, 0, 0);
    if (n < M){
      int cb = colbase + quad*4;
      float r0=0.f, r1=0.f, r2=0.f, r3=0.f;
      if (cb >= 1056){
        r0 = ldw(rb, rboff+cb-1056, f); r1 = ldw(rb, rboff+cb-1055, f);
        r2 = ldw(rb, rboff+cb-1054, f); r3 = ldw(rb, rboff+cb-1053, f);
      }
      u32 lo = (u32)f2b(acc[0]+r0) | ((u32)f2b(acc[1]+r1) << 16);
      u32 hi = (u32)f2b(acc[2]+r2) | ((u32)f2b(acc[3]+r3) << 16);
      *(uint2*)(T + (size_t)n*TCOLS + cb) = make_uint2(lo, hi);
    }
  }
}

// ---------- CSR node-major fused edge MLP + message + scatter ----------
// block = 16 consecutive src nodes; their T rows staged once in LDS (streamed,
// coalesced); edges of the window come from the contiguous perm slice.
__global__ __launch_bounds__(256) void k_edge_msg_csr(const int* __restrict__ src, const int* __restrict__ dst,
                             const int* __restrict__ perm, const int* __restrict__ offs, int M, int E_,
                             const void* __restrict__ ef,
                             const void* __restrict__ w1, long w1off,
                             const void* __restrict__ b1, long b1off,
                             const int* __restrict__ flag,
                             const u16* __restrict__ T, float* __restrict__ agg){
  __shared__ __align__(16) u16 Ts[16][1096];   // row stride 2192B: 16B-aligned, bank-offset 4/row
  __shared__ float w1s[256], b1s[32], efs[16][8], hs[16][34];
  __shared__ int pe[16], psrc[16], pdst[16];
  int tid = threadIdx.x;
  int n0 = blockIdx.x * 16;
  int f = *flag;
  w1s[tid] = ldw(w1, w1off + tid, f);
  if (tid < 32) b1s[tid] = ldw(b1, b1off + tid, f);
  // stage 16 T rows (2176B each) via coalesced uint4
  for (int idx = tid; idx < 16*136; idx += 256){
    int r = idx / 136, cw = idx - r*136;
    int n = n0 + r;
    uint4 v = make_uint4(0,0,0,0);
    if (n < M) v = *(const uint4*)(T + (size_t)n*TCOLS + cw*8);
    *(uint4*)&Ts[r][cw*8] = v;
  }
  int lo = offs[n0];
  int n1 = n0 + 16;
  int hi = (n1 < M) ? offs[n1] : E_;
  __syncthreads();
  int el = tid >> 4, kk = tid & 15;
  for (int base = lo; base < hi; base += 16){
    if (tid < 16){
      int ii = base + tid;
      int ee = (ii < hi) ? perm[ii] : -1;
      pe[tid] = ee;
      psrc[tid] = (ee >= 0) ? src[ee] - n0 : 0;
      pdst[tid] = (ee >= 0) ? dst[ee] : 0;
    }
    __syncthreads();
    int e = pe[el];
    if (kk < 8) efs[el][kk] = (e >= 0) ? ldw(ef, (long)e*8 + kk, f) : 0.f;
    __syncthreads();
    {
      float a0 = b1s[2*kk], a1 = b1s[2*kk+1];
      #pragma unroll
      for (int j = 0; j < 8; j++){
        float ev = efs[el][j];
        a0 += ev * w1s[j*32 + 2*kk];
        a1 += ev * w1s[j*32 + 2*kk+1];
      }
      hs[el][2*kk]   = fmaxf(a0, 0.f);
      hs[el][2*kk+1] = fmaxf(a1, 0.f);
      if (kk == 0) hs[el][32] = 1.0f;
    }
    __syncthreads();
    if (e >= 0){
      int r = psrc[el];
      float m0 = 0.f, m1 = 0.f;
      #pragma unroll
      for (int k = 0; k < 33; k++){
        u32 v = *(const u32*)&Ts[r][k*32 + 2*kk];
        float hk = hs[el][k];
        m0 += hk * bfl(v);
        m1 += hk * bfh(v);
      }
      float* ap = agg + (size_t)pdst[el]*32 + 2*kk;
      atomicAdd(ap,   m0);
      atomicAdd(ap+1, m1);
    }
    __syncthreads();
  }
}

// ---------- fused: feat = relu(agg/deg + Troot); m = feat @ w + b ----------
__global__ __launch_bounds__(256) void k_update_lin(const float* __restrict__ agg, const int* __restrict__ deg,
                           const u16* __restrict__ T, int M,
                           const void* __restrict__ w, long woff,
                           const void* __restrict__ b, long boff,
                           const int* __restrict__ flag,
                           float* __restrict__ feat, float* __restrict__ m_out){
  __shared__ float wsm[1024], bs[32], rows[8][33];
  int tid = threadIdx.x;
  int f = *flag;
  for (int idx = tid; idx < 1024; idx += 256) wsm[idx] = ldw(w, woff + idx, f);
  if (tid < 32) bs[tid] = ldw(b, boff + tid, f);
  int nl = tid >> 5, o = tid & 31;
  int n = blockIdx.x*8 + nl;
  if (n < M){
    int dg = deg[n];
    float d = (float)(dg > 1 ? dg : 1);
    float v = fmaxf(agg[(size_t)n*32 + o]/d + b2f(T[(size_t)n*TCOLS + 1056 + o]), 0.f);
    rows[nl][o] = v;
    feat[(size_t)n*32 + o] = v;
  }
  __syncthreads();
  if (n >= M) return;
  float acc = bs[o];
  #pragma unroll
  for (int j = 0; j < 32; j++) acc += rows[nl][j]*wsm[j*32+o];
  m_out[(size_t)n*32 + o] = acc;
}

__global__ __launch_bounds__(256) void k_scatter(const int* __restrict__ gidx, const int* __restrict__ sidx, int A_,
                          const float* __restrict__ m, float* __restrict__ agg){
  int i = blockIdx.x*256 + threadIdx.x;
  if (i >= A_*32) return;
  int a = i >> 5, o = i & 31;
  atomicAdd(&agg[(size_t)sidx[a]*32 + o], m[(size_t)gidx[a]*32 + o]);
}

// ---------- final store: x = xC + aggS1/deg, c = cC1 ----------
__global__ __launch_bounds__(256) void k_store(const float* __restrict__ x, const float* __restrict__ xagg,
                      const int* __restrict__ xdeg, const float* __restrict__ c,
                      void* __restrict__ out, const int* __restrict__ flag){
  int i = blockIdx.x*256 + threadIdx.x;
  int tot = Nn*32 + NCc*32;
  if (i >= tot) return;
  float v;
  if (i < Nn*32){
    int n = i >> 5;
    int dg = xdeg[n];
    float d = (float)(dg > 1 ? dg : 1);
    v = x[i] + xagg[i]/d;
  } else v = c[i - Nn*32];
  if (*flag) ((float*)out)[i] = v;
  else       ((u16*)out)[i]   = f2b(v);
}

extern "C" void kernel_launch(void* const* d_in, const int* in_sizes, int n_in,
                              void* d_out, int out_size, void* d_ws, size_t ws_size,
                              hipStream_t stream){
  const int* ei  = (const int*)d_in[1];
  const int* n2c = (const int*)d_in[4];
  const int* cei = (const int*)d_in[5];
  const void *efr = d_in[2], *cefr = d_in[6];
  const void *nn1w = d_in[7], *nn1b = d_in[8], *nn2w = d_in[9], *nn2b = d_in[10],
             *rootw = d_in[11], *rootb = d_in[12], *n2cw = d_in[13], *n2cb = d_in[14],
             *cnn1w = d_in[15], *cnn1b = d_in[16], *cnn2w = d_in[17], *cnn2b = d_in[18],
             *crootw = d_in[19], *crootb = d_in[20], *c2nw = d_in[21], *c2nb = d_in[22];

  char* ws = (char*)d_ws;
  size_t off = 0;
  auto alloc = [&](size_t bytes){ void* p = ws + off; off += (bytes + 255) & ~(size_t)255; return p; };

  // ---- zeroed region (single memset) ----
  size_t zstart = off;
  float *aggE[2], *caggS[2], *caggE[2], *aggS[2];
  for (int l = 0; l < 2; l++){
    aggE[l]  = (float*)alloc((size_t)Nn*32*4);
    caggS[l] = (float*)alloc((size_t)NCc*32*4);
    caggE[l] = (float*)alloc((size_t)NCc*32*4);
    aggS[l]  = (float*)alloc((size_t)Nn*32*4);
  }
  int* deg_nd  = (int*)alloc((size_t)Nn*4);
  int* deg_ce  = (int*)alloc((size_t)NCc*4);
  int* deg_n2c = (int*)alloc((size_t)NCc*4);
  int* deg_c2n = (int*)alloc((size_t)Nn*4);
  int* cnt_sn  = (int*)alloc((size_t)Nn*4);
  int* cnt_sc  = (int*)alloc((size_t)NCc*4);
  int* cur_n   = (int*)alloc((size_t)Nn*4);
  int* cur_c   = (int*)alloc((size_t)NCc*4);
  u32* maxbits = (u32*)alloc(256);
  int* zcnt = (int*)((char*)maxbits + 4);
  int* flag = (int*)((char*)maxbits + 8);
  int* done = (int*)((char*)maxbits + 12);
  size_t zbytes = off - zstart;

  // ---- non-zeroed ----
  float* xA  = (float*)alloc((size_t)Nn*32*4);
  float* xB  = (float*)alloc((size_t)Nn*32*4);
  float* xC  = (float*)alloc((size_t)Nn*32*4);
  float* cA  = (float*)alloc((size_t)NCc*32*4);
  float* cC0 = (float*)alloc((size_t)NCc*32*4);
  float* cC1 = (float*)alloc((size_t)NCc*32*4);
  float* m   = (float*)alloc((size_t)Nn*32*4);
  int* offs_n = (int*)alloc((size_t)Nn*4);
  int* offs_c = (int*)alloc((size_t)NCc*4);
  int* perm_n = (int*)alloc((size_t)Ee*4);
  int* perm_c = (int*)alloc((size_t)ECc*4);
  u16* Wp4 = (u16*)alloc((size_t)4*WPSZ*2);
  u16* Tb  = (u16*)alloc((size_t)Nn*TCOLS*2);

  auto nb = [](int n){ return (n + 255)/256; };

  // 1. single memset of accumulators/counters
  hipMemsetAsync(ws + zstart, 0, zbytes, stream);
  // 2. dtype detect + flag (fused)
  k_detect<<<256,256,0,stream>>>((const u16*)d_in[0], Nn*32, maxbits, zcnt, done, flag);
  // 3. features -> f32
  k_conv_all<<<nb(Nn*32 + NCc*32),256,0,stream>>>(d_in[0], d_in[3], xA, cA, flag);
  // 4. histograms + counting-sort (CSR by src)
  k_count_all<<<nb(2*Ee + 2*ECc + 2*Aa),256,0,stream>>>(ei, cei, n2c,
      deg_nd, deg_ce, deg_n2c, deg_c2n, cnt_sn, cnt_sc);
  k_scan_all<<<1,1024,0,stream>>>(cnt_sn, cnt_sc, offs_n, offs_c);
  k_place<<<nb(Ee+ECc),256,0,stream>>>(ei, cei, offs_n, offs_c, cur_n, cur_c, perm_n, perm_c);
  // 5. pack all weights
  k_wpack_all<<<nb(4*WPSZ),256,0,stream>>>(nn2w, nn2b, rootw, cnn2w, cnn2b, crootw, flag, Wp4);

  int Gn = (Nn + 15)/16, Gc = (NCc + 15)/16;

  // ---- layer 0 ----
  k_feat_gemm_mfma<<<dim3((Nn+63)/64,4),256,0,stream>>>(xA, nullptr, nullptr, Nn,
      Wp4 + 0*WPSZ, rootb, 0, flag, Tb);
  k_edge_msg_csr<<<Gn,256,0,stream>>>(ei, ei+Ee, perm_n, offs_n, Nn, Ee, efr,
      nn1w, 0, nn1b, 0, flag, Tb, aggE[0]);
  k_update_lin<<<(Nn+7)/8,256,0,stream>>>(aggE[0], deg_nd, Tb, Nn, n2cw, 0, n2cb, 0, flag, xB, m);
  k_scatter<<<nb(Aa*32),256,0,stream>>>(n2c, n2c+Aa, Aa, m, caggS[0]);
  k_feat_gemm_mfma<<<dim3((NCc+63)/64,4),256,0,stream>>>(cA, caggS[0], deg_n2c, NCc,
      Wp4 + 1*WPSZ, crootb, 0, flag, Tb);
  k_edge_msg_csr<<<Gc,256,0,stream>>>(cei, cei+ECc, perm_c, offs_c, NCc, ECc, cefr,
      cnn1w, 0, cnn1b, 0, flag, Tb, caggE[0]);
  k_update_lin<<<(NCc+7)/8,256,0,stream>>>(caggE[0], deg_ce, Tb, NCc, c2nw, 0, c2nb, 0, flag, cC0, m);
  k_scatter<<<nb(Aa*32),256,0,stream>>>(n2c+Aa, n2c, Aa, m, aggS[0]);
  // ---- layer 1 ----
  k_feat_gemm_mfma<<<dim3((Nn+63)/64,4),256,0,stream>>>(xB, aggS[0], deg_c2n, Nn,
      Wp4 + 2*WPSZ, rootb, 32, flag, Tb);
  k_edge_msg_csr<<<Gn,256,0,stream>>>(ei, ei+Ee, perm_n, offs_n, Nn, Ee, efr,
      nn1w, 256, nn1b, 32, flag, Tb, aggE[1]);
  k_update_lin<<<(Nn+7)/8,256,0,stream>>>(aggE[1], deg_nd, Tb, Nn, n2cw, 1024, n2cb, 32, flag, xC, m);
  k_scatter<<<nb(Aa*32),256,0,stream>>>(n2c, n2c+Aa, Aa, m, caggS[1]);
  k_feat_gemm_mfma<<<dim3((NCc+63)/64,4),256,0,stream>>>(cC0, caggS[1], deg_n2c, NCc,
      Wp4 + 3*WPSZ, crootb, 32, flag, Tb);
  k_edge_msg_csr<<<Gc,256,0,stream>>>(cei, cei+ECc, perm_c, offs_c, NCc, ECc, cefr,
      cnn1w, 256, cnn1b, 32, flag, Tb, caggE[1]);
  k_update_lin<<<(NCc+7)/8,256,0,stream>>>(caggE[1], deg_ce, Tb, NCc, c2nw, 1024, c2nb, 32, flag, cC1, m);
  k_scatter<<<nb(Aa*32),256,0,stream>>>(n2c+Aa, n2c, Aa, m, aggS[1]);
  // ---- output ----
  k_store<<<nb(Nn*32 + NCc*32),256,0,stream>>>(xC, aggS[1], deg_c2n, cC1, d_out, flag);
}

// Round 7
// 386.895 us; speedup vs baseline: 1.1463x; 1.1463x over previous
//
#include <hip/hip_runtime.h>
#include <hip/hip_bf16.h>

typedef unsigned int u32;
typedef unsigned short u16;

#define DEVINL __device__ __forceinline__

constexpr int Nn  = 25000;
constexpr int Ee  = 100000;
constexpr int NCc = 8000;
constexpr int Aa  = 50000;
constexpr int ECc = 24000;
constexpr int TCOLS = 1088;     // 34 k-rows * 32 o-cols
constexpr int WPSZ  = TCOLS*32; // one packed weight set
constexpr int TSP   = 1064;     // LDS T row stride (u16): 1056 cols + 8 pad

typedef float f32x4 __attribute__((ext_vector_type(4)));
typedef short s16x8 __attribute__((ext_vector_type(8)));

DEVINL float b2f(u16 u){ union{u32 i;float f;}v; v.i = ((u32)u)<<16; return v.f; }
DEVINL float bfl(u32 u){ union{u32 i;float f;}v; v.i = u<<16; return v.f; }
DEVINL float bfh(u32 u){ union{u32 i;float f;}v; v.i = u & 0xffff0000u; return v.f; }
DEVINL u16 f2b(float f){ union{float f;u32 i;}v; v.f=f; u32 i=v.i;
  return (u16)((i + 0x7fffu + ((i>>16)&1u)) >> 16); }
DEVINL float ldw(const void* p, long i, int f){
  return f ? ((const float*)p)[i] : b2f(((const u16*)p)[i]);
}

// ---------- dtype detection + flag (fused via last-block-done) ----------
__global__ __launch_bounds__(256) void k_detect(const u16* __restrict__ p, int n,
                        u32* __restrict__ maxbits, int* __restrict__ zcnt,
                        int* __restrict__ done, int* __restrict__ flag){
  int i0 = blockIdx.x*256 + threadIdx.x;
  float lm = 0.f; int lz = 0;
  for (int i = i0; i < n; i += gridDim.x*256){
    u16 v = p[i];
    if (v == 0) lz++;
    lm = fmaxf(lm, fabsf(b2f(v)));
  }
  #pragma unroll
  for (int off = 32; off; off >>= 1){
    lm = fmaxf(lm, __shfl_down(lm, off));
    lz += __shfl_down(lz, off);
  }
  if ((threadIdx.x & 63) == 0){
    atomicMax(maxbits, __float_as_uint(lm));
    atomicAdd(zcnt, lz);
  }
  __syncthreads();
  if (threadIdx.x == 0){
    __threadfence();
    if (atomicAdd(done, 1) == gridDim.x - 1){
      float m = __uint_as_float(*maxbits);
      *flag = (m > 1e6f || *zcnt > n/4) ? 1 : 0;   // 1 => inputs are f32
    }
  }
}

// ---------- convert both feature tensors in one grid ----------
__global__ __launch_bounds__(256) void k_conv_all(const void* __restrict__ xin, const void* __restrict__ cin,
                         float* __restrict__ xA, float* __restrict__ cA, const int* __restrict__ flag){
  int i = blockIdx.x*256 + threadIdx.x;
  int f = *flag;
  if (i < Nn*32) xA[i] = ldw(xin, i, f);
  else { i -= Nn*32; if (i < NCc*32) cA[i] = ldw(cin, i, f); }
}

// ---------- all degree/count histograms in one kernel ----------
__global__ __launch_bounds__(256) void k_count_all(const int* __restrict__ ei, const int* __restrict__ cei,
                          const int* __restrict__ n2c,
                          int* __restrict__ deg_nd, int* __restrict__ deg_ce,
                          int* __restrict__ deg_n2c, int* __restrict__ deg_c2n,
                          int* __restrict__ cnt_sn, int* __restrict__ cnt_sc){
  int i = blockIdx.x*256 + threadIdx.x;
  if (i < Ee)                             atomicAdd(&deg_nd[ei[Ee + i]], 1);
  else if ((i -= Ee) < ECc)               atomicAdd(&deg_ce[cei[ECc + i]], 1);
  else if ((i -= ECc) < Aa)               atomicAdd(&deg_n2c[n2c[Aa + i]], 1);
  else if ((i -= Aa) < Aa)                atomicAdd(&deg_c2n[n2c[i]], 1);
  else if ((i -= Aa) < Ee)                atomicAdd(&cnt_sn[ei[i]], 1);
  else if ((i -= Ee) < ECc)               atomicAdd(&cnt_sc[cei[i]], 1);
}

// ---------- single-kernel exclusive scan (1024 threads, wave-scan) ----------
__global__ __launch_bounds__(1024) void k_scan_all(const int* __restrict__ cnt_n, const int* __restrict__ cnt_c,
                          int* __restrict__ offs_n, int* __restrict__ offs_c){
  __shared__ int wsum[16], wpre[16];
  __shared__ int carry_s;
  int tid = threadIdx.x, lane = tid & 63, w = tid >> 6;
  for (int pass = 0; pass < 2; pass++){
    const int* cnt = pass ? cnt_c : cnt_n;
    int* offs = pass ? offs_c : offs_n;
    int M = pass ? NCc : Nn;
    if (tid == 0) carry_s = 0;
    __syncthreads();
    for (int base = 0; base < M; base += 1024){
      int i = base + tid;
      int v = (i < M) ? cnt[i] : 0;
      int x = v;
      #pragma unroll
      for (int d = 1; d < 64; d <<= 1){ int t = __shfl_up(x, d); if (lane >= d) x += t; }
      if (lane == 63) wsum[w] = x;
      __syncthreads();
      if (w == 0){
        int t = (lane < 16) ? wsum[lane] : 0;
        int y = t;
        #pragma unroll
        for (int d = 1; d < 16; d <<= 1){ int t2 = __shfl_up(y, d); if (lane >= d) y += t2; }
        if (lane < 16) wpre[lane] = y - t;
      }
      __syncthreads();
      if (i < M) offs[i] = carry_s + wpre[w] + x - v;
      int tot = wpre[15] + wsum[15];
      __syncthreads();
      if (tid == 0) carry_s += tot;
      __syncthreads();
    }
  }
}

__global__ __launch_bounds__(256) void k_place(const int* __restrict__ ei, const int* __restrict__ cei,
                      const int* __restrict__ offs_n, const int* __restrict__ offs_c,
                      int* __restrict__ cur_n, int* __restrict__ cur_c,
                      int* __restrict__ perm_n, int* __restrict__ perm_c){
  int i = blockIdx.x*256 + threadIdx.x;
  if (i < Ee){
    int s = ei[i];
    perm_n[offs_n[s] + atomicAdd(&cur_n[s], 1)] = i;
  } else if ((i -= Ee) < ECc){
    int s = cei[i];
    perm_c[offs_c[s] + atomicAdd(&cur_c[s], 1)] = i;
  }
}

// ---------- pack all 4 weight sets at once: set = l*2 + isClique ----------
__global__ __launch_bounds__(256) void k_wpack_all(const void* __restrict__ nn2w, const void* __restrict__ nn2b,
                          const void* __restrict__ rootw,
                          const void* __restrict__ cnn2w, const void* __restrict__ cnn2b,
                          const void* __restrict__ crootw,
                          const int* __restrict__ flag, u16* __restrict__ Wp4){
  int i = blockIdx.x*256 + threadIdx.x;
  if (i >= 4*WPSZ) return;
  int set = i / WPSZ, j = i - set*WPSZ;
  int l = set >> 1, isC = set & 1;
  const void* W2 = isC ? cnn2w : nn2w;
  const void* B2 = isC ? cnn2b : nn2b;
  const void* RW = isC ? crootw : rootw;
  int f = *flag;
  int col = j >> 5, ii = j & 31;
  float v;
  if (col < 1024)      v = ldw(W2, (long)l*32768 + ((col>>5)<<10) + (ii<<5) + (col&31), f);
  else if (col < 1056) v = ldw(B2, (long)l*1024 + (ii<<5) + (col-1024), f);
  else                 v = ldw(RW, (long)l*1024 + (ii<<5) + (col-1056), f);
  Wp4[i] = f2b(v);
}

// ---------- fused conv: MFMA T-tile into LDS + wave-autonomous CSR edge loop ----------
// block = 16 consecutive src nodes. Phase 1: T[16 x 1056] in LDS via MFMA
// (17 col-tiles per wave); root cols (1056..1087)+rb -> feat_root (f32, global).
// Phase 2 (no barriers): each wave takes 4 edges/iter from the window's perm
// slice; h from wave-private LDS; msg from Ts; fire-and-forget atomics.
__global__ __launch_bounds__(256) void k_conv_fused(const float* __restrict__ base,
                           const float* __restrict__ addagg, const int* __restrict__ adddeg, int M,
                           const int* __restrict__ src, const int* __restrict__ dst,
                           const int* __restrict__ perm, const int* __restrict__ offs, int E_,
                           const void* __restrict__ ef,
                           const void* __restrict__ w1, long w1off,
                           const void* __restrict__ b1, long b1off,
                           const u16* __restrict__ Wp,
                           const void* __restrict__ rb, long rboff,
                           const int* __restrict__ flag,
                           float* __restrict__ feat_root, float* __restrict__ agg){
  __shared__ __align__(16) u16 Ts[16*TSP];
  __shared__ float w1s[256], b1s[32];
  __shared__ float efs[4][4][8];
  __shared__ float hw[4][4][34];
  int tid = threadIdx.x;
  int w = tid >> 6, lane = tid & 63;
  int quad = lane >> 4, lm = lane & 15;
  int n0 = blockIdx.x * 16;
  int f = *flag;
  w1s[tid] = ldw(w1, w1off + tid, f);
  if (tid < 32) b1s[tid] = ldw(b1, b1off + tid, f);
  // x fragment for the 16 window nodes (residual-mean folded)
  int n = n0 + lm;
  int nc = n < M ? n : M-1;
  const float* bp = base + (size_t)nc*32 + quad*8;
  s16x8 bfrag;
  if (addagg){
    int dg = adddeg[nc];
    float d = (float)(dg > 1 ? dg : 1);
    const float* ap = addagg + (size_t)nc*32 + quad*8;
    #pragma unroll
    for (int j = 0; j < 8; j++) bfrag[j] = (short)f2b(bp[j] + ap[j]/d);
  } else {
    #pragma unroll
    for (int j = 0; j < 8; j++) bfrag[j] = (short)f2b(bp[j]);
  }
  // phase 1: T tile via MFMA (wave w -> col-tiles [17w, 17w+17))
  #pragma unroll 1
  for (int ti = 0; ti < 17; ti++){
    int ct = w*17 + ti;
    int colbase = ct*16;
    s16x8 afrag = *(const s16x8*)(Wp + (size_t)(colbase + lm)*32 + quad*8);
    f32x4 acc = {0.f, 0.f, 0.f, 0.f};
    acc = __builtin_amdgcn_mfma_f32_16x16x32_bf16(afrag, bfrag, acc, 0, 0, 0);
    int cb = colbase + quad*4;   // lane holds node=lm, cols cb..cb+3
    if (ct < 66){
      u32 lo = (u32)f2b(acc[0]) | ((u32)f2b(acc[1]) << 16);
      u32 hi = (u32)f2b(acc[2]) | ((u32)f2b(acc[3]) << 16);
      *(uint2*)&Ts[lm*TSP + cb] = make_uint2(lo, hi);
    } else if (n < M){
      int o = cb - 1056;
      float4 v = make_float4(acc[0] + ldw(rb, rboff+o,   f),
                             acc[1] + ldw(rb, rboff+o+1, f),
                             acc[2] + ldw(rb, rboff+o+2, f),
                             acc[3] + ldw(rb, rboff+o+3, f));
      *(float4*)&feat_root[(size_t)n*32 + o] = v;
    }
  }
  __syncthreads();
  // phase 2: wave-autonomous edges (4 per wave-iteration)
  int lo = offs[n0];
  int n1 = n0 + 16;
  int hi = (n1 < M) ? offs[n1] : E_;
  int eg = quad, kk = lm;
  if (kk == 0) hw[w][eg][32] = 1.0f;
  for (int bi = lo + w*4; bi < hi; bi += 16){
    int ii = bi + eg;
    int e = (ii < hi) ? perm[ii] : -1;
    int sr = 0, dn = 0;
    if (e >= 0){ sr = src[e] - n0; dn = dst[e]; }
    if (kk < 8) efs[w][eg][kk] = (e >= 0) ? ldw(ef, (long)e*8 + kk, f) : 0.f;
    // same-wave LDS RAW: lgkmcnt only, no barrier
    float a0 = b1s[2*kk], a1 = b1s[2*kk+1];
    #pragma unroll
    for (int j = 0; j < 8; j++){
      float ev = efs[w][eg][j];
      a0 += ev * w1s[j*32 + 2*kk];
      a1 += ev * w1s[j*32 + 2*kk+1];
    }
    hw[w][eg][2*kk]   = fmaxf(a0, 0.f);
    hw[w][eg][2*kk+1] = fmaxf(a1, 0.f);
    if (e >= 0){
      const u16* Tr = &Ts[sr*TSP];
      float m0 = 0.f, m1 = 0.f;
      #pragma unroll
      for (int k = 0; k < 33; k++){
        u32 v = *(const u32*)&Tr[k*32 + 2*kk];
        float hk = hw[w][eg][k];
        m0 += hk * bfl(v);
        m1 += hk * bfh(v);
      }
      float* ap = agg + (size_t)dn*32 + 2*kk;
      atomicAdd(ap,   m0);
      atomicAdd(ap+1, m1);
    }
  }
}

// ---------- fused: feat = relu(agg/deg + feat_root); m = feat @ w + b ----------
__global__ __launch_bounds__(256) void k_update_lin(const float* __restrict__ agg, const int* __restrict__ deg,
                           const float* __restrict__ feat_root, int M,
                           const void* __restrict__ w, long woff,
                           const void* __restrict__ b, long boff,
                           const int* __restrict__ flag,
                           float* __restrict__ feat, float* __restrict__ m_out){
  __shared__ float wsm[1024], bs[32], rows[8][33];
  int tid = threadIdx.x;
  int f = *flag;
  for (int idx = tid; idx < 1024; idx += 256) wsm[idx] = ldw(w, woff + idx, f);
  if (tid < 32) bs[tid] = ldw(b, boff + tid, f);
  int nl = tid >> 5, o = tid & 31;
  int n = blockIdx.x*8 + nl;
  if (n < M){
    int dg = deg[n];
    float d = (float)(dg > 1 ? dg : 1);
    float v = fmaxf(agg[(size_t)n*32 + o]/d + feat_root[(size_t)n*32 + o], 0.f);
    rows[nl][o] = v;
    feat[(size_t)n*32 + o] = v;
  }
  __syncthreads();
  if (n >= M) return;
  float acc = bs[o];
  #pragma unroll
  for (int j = 0; j < 32; j++) acc += rows[nl][j]*wsm[j*32+o];
  m_out[(size_t)n*32 + o] = acc;
}

__global__ __launch_bounds__(256) void k_scatter(const int* __restrict__ gidx, const int* __restrict__ sidx, int A_,
                          const float* __restrict__ m, float* __restrict__ agg){
  int i = blockIdx.x*256 + threadIdx.x;
  if (i >= A_*32) return;
  int a = i >> 5, o = i & 31;
  atomicAdd(&agg[(size_t)sidx[a]*32 + o], m[(size_t)gidx[a]*32 + o]);
}

// ---------- final store: x = xC + aggS1/deg, c = cC1 ----------
__global__ __launch_bounds__(256) void k_store(const float* __restrict__ x, const float* __restrict__ xagg,
                      const int* __restrict__ xdeg, const float* __restrict__ c,
                      void* __restrict__ out, const int* __restrict__ flag){
  int i = blockIdx.x*256 + threadIdx.x;
  int tot = Nn*32 + NCc*32;
  if (i >= tot) return;
  float v;
  if (i < Nn*32){
    int n = i >> 5;
    int dg = xdeg[n];
    float d = (float)(dg > 1 ? dg : 1);
    v = x[i] + xagg[i]/d;
  } else v = c[i - Nn*32];
  if (*flag) ((float*)out)[i] = v;
  else       ((u16*)out)[i]   = f2b(v);
}

extern "C" void kernel_launch(void* const* d_in, const int* in_sizes, int n_in,
                              void* d_out, int out_size, void* d_ws, size_t ws_size,
                              hipStream_t stream){
  const int* ei  = (const int*)d_in[1];
  const int* n2c = (const int*)d_in[4];
  const int* cei = (const int*)d_in[5];
  const void *efr = d_in[2], *cefr = d_in[6];
  const void *nn1w = d_in[7], *nn1b = d_in[8], *nn2w = d_in[9], *nn2b = d_in[10],
             *rootw = d_in[11], *rootb = d_in[12], *n2cw = d_in[13], *n2cb = d_in[14],
             *cnn1w = d_in[15], *cnn1b = d_in[16], *cnn2w = d_in[17], *cnn2b = d_in[18],
             *crootw = d_in[19], *crootb = d_in[20], *c2nw = d_in[21], *c2nb = d_in[22];

  char* ws = (char*)d_ws;
  size_t off = 0;
  auto alloc = [&](size_t bytes){ void* p = ws + off; off += (bytes + 255) & ~(size_t)255; return p; };

  // ---- zeroed region (single memset) ----
  size_t zstart = off;
  float *aggE[2], *caggS[2], *caggE[2], *aggS[2];
  for (int l = 0; l < 2; l++){
    aggE[l]  = (float*)alloc((size_t)Nn*32*4);
    caggS[l] = (float*)alloc((size_t)NCc*32*4);
    caggE[l] = (float*)alloc((size_t)NCc*32*4);
    aggS[l]  = (float*)alloc((size_t)Nn*32*4);
  }
  int* deg_nd  = (int*)alloc((size_t)Nn*4);
  int* deg_ce  = (int*)alloc((size_t)NCc*4);
  int* deg_n2c = (int*)alloc((size_t)NCc*4);
  int* deg_c2n = (int*)alloc((size_t)Nn*4);
  int* cnt_sn  = (int*)alloc((size_t)Nn*4);
  int* cnt_sc  = (int*)alloc((size_t)NCc*4);
  int* cur_n   = (int*)alloc((size_t)Nn*4);
  int* cur_c   = (int*)alloc((size_t)NCc*4);
  u32* maxbits = (u32*)alloc(256);
  int* zcnt = (int*)((char*)maxbits + 4);
  int* flag = (int*)((char*)maxbits + 8);
  int* done = (int*)((char*)maxbits + 12);
  size_t zbytes = off - zstart;

  // ---- non-zeroed ----
  float* xA  = (float*)alloc((size_t)Nn*32*4);
  float* xB  = (float*)alloc((size_t)Nn*32*4);
  float* xC  = (float*)alloc((size_t)Nn*32*4);
  float* cA  = (float*)alloc((size_t)NCc*32*4);
  float* cC0 = (float*)alloc((size_t)NCc*32*4);
  float* cC1 = (float*)alloc((size_t)NCc*32*4);
  float* m   = (float*)alloc((size_t)Nn*32*4);
  float* frn = (float*)alloc((size_t)Nn*32*4);    // feat_root (node)
  float* frc = (float*)alloc((size_t)NCc*32*4);   // feat_root (clique)
  int* offs_n = (int*)alloc((size_t)Nn*4);
  int* offs_c = (int*)alloc((size_t)NCc*4);
  int* perm_n = (int*)alloc((size_t)Ee*4);
  int* perm_c = (int*)alloc((size_t)ECc*4);
  u16* Wp4 = (u16*)alloc((size_t)4*WPSZ*2);

  auto nb = [](int n){ return (n + 255)/256; };

  // 1. single memset of accumulators/counters
  hipMemsetAsync(ws + zstart, 0, zbytes, stream);
  // 2. dtype detect + flag
  k_detect<<<256,256,0,stream>>>((const u16*)d_in[0], Nn*32, maxbits, zcnt, done, flag);
  // 3. features -> f32
  k_conv_all<<<nb(Nn*32 + NCc*32),256,0,stream>>>(d_in[0], d_in[3], xA, cA, flag);
  // 4. histograms + counting-sort (CSR by src)
  k_count_all<<<nb(2*Ee + 2*ECc + 2*Aa),256,0,stream>>>(ei, cei, n2c,
      deg_nd, deg_ce, deg_n2c, deg_c2n, cnt_sn, cnt_sc);
  k_scan_all<<<1,1024,0,stream>>>(cnt_sn, cnt_sc, offs_n, offs_c);
  k_place<<<nb(Ee+ECc),256,0,stream>>>(ei, cei, offs_n, offs_c, cur_n, cur_c, perm_n, perm_c);
  // 5. pack all weights
  k_wpack_all<<<nb(4*WPSZ),256,0,stream>>>(nn2w, nn2b, rootw, cnn2w, cnn2b, crootw, flag, Wp4);

  int Gn = (Nn + 15)/16, Gc = (NCc + 15)/16;

  // ---- layer 0 ----
  k_conv_fused<<<Gn,256,0,stream>>>(xA, nullptr, nullptr, Nn, ei, ei+Ee, perm_n, offs_n, Ee,
      efr, nn1w, 0, nn1b, 0, Wp4 + 0*WPSZ, rootb, 0, flag, frn, aggE[0]);
  k_update_lin<<<(Nn+7)/8,256,0,stream>>>(aggE[0], deg_nd, frn, Nn, n2cw, 0, n2cb, 0, flag, xB, m);
  k_scatter<<<nb(Aa*32),256,0,stream>>>(n2c, n2c+Aa, Aa, m, caggS[0]);
  k_conv_fused<<<Gc,256,0,stream>>>(cA, caggS[0], deg_n2c, NCc, cei, cei+ECc, perm_c, offs_c, ECc,
      cefr, cnn1w, 0, cnn1b, 0, Wp4 + 1*WPSZ, crootb, 0, flag, frc, caggE[0]);
  k_update_lin<<<(NCc+7)/8,256,0,stream>>>(caggE[0], deg_ce, frc, NCc, c2nw, 0, c2nb, 0, flag, cC0, m);
  k_scatter<<<nb(Aa*32),256,0,stream>>>(n2c+Aa, n2c, Aa, m, aggS[0]);
  // ---- layer 1 ----
  k_conv_fused<<<Gn,256,0,stream>>>(xB, aggS[0], deg_c2n, Nn, ei, ei+Ee, perm_n, offs_n, Ee,
      efr, nn1w, 256, nn1b, 32, Wp4 + 2*WPSZ, rootb, 32, flag, frn, aggE[1]);
  k_update_lin<<<(Nn+7)/8,256,0,stream>>>(aggE[1], deg_nd, frn, Nn, n2cw, 1024, n2cb, 32, flag, xC, m);
  k_scatter<<<nb(Aa*32),256,0,stream>>>(n2c, n2c+Aa, Aa, m, caggS[1]);
  k_conv_fused<<<Gc,256,0,stream>>>(cC0, caggS[1], deg_n2c, NCc, cei, cei+ECc, perm_c, offs_c, ECc,
      cefr, cnn1w, 256, cnn1b, 32, Wp4 + 3*WPSZ, crootb, 32, flag, frc, caggE[1]);
  k_update_lin<<<(NCc+7)/8,256,0,stream>>>(caggE[1], deg_ce, frc, NCc, c2nw, 1024, c2nb, 32, flag, cC1, m);
  k_scatter<<<nb(Aa*32),256,0,stream>>>(n2c+Aa, n2c, Aa, m, aggS[1]);
  // ---- output ----
  k_store<<<nb(Nn*32 + NCc*32),256,0,stream>>>(xC, aggS[1], deg_c2n, cC1, d_out, flag);
}

// Round 8
// 360.148 us; speedup vs baseline: 1.2314x; 1.0743x over previous
//
#include <hip/hip_runtime.h>
#include <hip/hip_bf16.h>

typedef unsigned int u32;
typedef unsigned short u16;

#define DEVINL __device__ __forceinline__

constexpr int Nn  = 25000;
constexpr int Ee  = 100000;
constexpr int NCc = 8000;
constexpr int Aa  = 50000;
constexpr int ECc = 24000;
constexpr int TCOLS = 1088;     // 34 k-rows * 32 o-cols
constexpr int WPSZ  = TCOLS*32; // one packed weight set
constexpr int TSP   = 1064;     // LDS T row stride (u16)
constexpr int NB_N = (Nn + 255)/256;   // 98 scan blocks (node)
constexpr int NB_C = (NCc + 255)/256;  // 32 scan blocks (clique)

typedef float f32x4 __attribute__((ext_vector_type(4)));
typedef short s16x8 __attribute__((ext_vector_type(8)));

DEVINL float b2f(u16 u){ union{u32 i;float f;}v; v.i = ((u32)u)<<16; return v.f; }
DEVINL float bfl(u32 u){ union{u32 i;float f;}v; v.i = u<<16; return v.f; }
DEVINL float bfh(u32 u){ union{u32 i;float f;}v; v.i = u & 0xffff0000u; return v.f; }
DEVINL u16 f2b(float f){ union{float f;u32 i;}v; v.f=f; u32 i=v.i;
  return (u16)((i + 0x7fffu + ((i>>16)&1u)) >> 16); }
DEVINL float ldw(const void* p, long i, int f){
  return f ? ((const float*)p)[i] : b2f(((const u16*)p)[i]);
}

// ---------- dtype detection + flag (fused via last-block-done) ----------
__global__ __launch_bounds__(256) void k_detect(const u16* __restrict__ p, int n,
                        u32* __restrict__ maxbits, int* __restrict__ zcnt,
                        int* __restrict__ done, int* __restrict__ flag){
  int i0 = blockIdx.x*256 + threadIdx.x;
  float lm = 0.f; int lz = 0;
  for (int i = i0; i < n; i += gridDim.x*256){
    u16 v = p[i];
    if (v == 0) lz++;
    lm = fmaxf(lm, fabsf(b2f(v)));
  }
  #pragma unroll
  for (int off = 32; off; off >>= 1){
    lm = fmaxf(lm, __shfl_down(lm, off));
    lz += __shfl_down(lz, off);
  }
  if ((threadIdx.x & 63) == 0){
    atomicMax(maxbits, __float_as_uint(lm));
    atomicAdd(zcnt, lz);
  }
  __syncthreads();
  if (threadIdx.x == 0){
    __threadfence();
    if (atomicAdd(done, 1) == gridDim.x - 1){
      float m = __uint_as_float(*maxbits);
      *flag = (m > 1e6f || *zcnt > n/4) ? 1 : 0;   // 1 => inputs are f32
    }
  }
}

// ---------- convert both feature tensors in one grid ----------
__global__ __launch_bounds__(256) void k_conv_all(const void* __restrict__ xin, const void* __restrict__ cin,
                         float* __restrict__ xA, float* __restrict__ cA, const int* __restrict__ flag){
  int i = blockIdx.x*256 + threadIdx.x;
  int f = *flag;
  if (i < Nn*32) xA[i] = ldw(xin, i, f);
  else { i -= Nn*32; if (i < NCc*32) cA[i] = ldw(cin, i, f); }
}

// ---------- all degree/count histograms in one kernel ----------
__global__ __launch_bounds__(256) void k_count_all(const int* __restrict__ ei, const int* __restrict__ cei,
                          const int* __restrict__ n2c,
                          int* __restrict__ deg_nd, int* __restrict__ deg_ce,
                          int* __restrict__ deg_n2c, int* __restrict__ deg_c2n,
                          int* __restrict__ cnt_sn, int* __restrict__ cnt_sc){
  int i = blockIdx.x*256 + threadIdx.x;
  if (i < Ee)                             atomicAdd(&deg_nd[ei[Ee + i]], 1);
  else if ((i -= Ee) < ECc)               atomicAdd(&deg_ce[cei[ECc + i]], 1);
  else if ((i -= ECc) < Aa)               atomicAdd(&deg_n2c[n2c[Aa + i]], 1);
  else if ((i -= Aa) < Aa)                atomicAdd(&deg_c2n[n2c[i]], 1);
  else if ((i -= Aa) < Ee)                atomicAdd(&cnt_sn[ei[i]], 1);
  else if ((i -= Ee) < ECc)               atomicAdd(&cnt_sc[cei[i]], 1);
}

// ---------- hierarchical scan (3 dispatches, R5-proven) ----------
__global__ __launch_bounds__(256) void k_scan_block(const int* __restrict__ cnt_n, const int* __restrict__ cnt_c,
                           int* __restrict__ offs_n, int* __restrict__ offs_c,
                           int* __restrict__ bsum_n, int* __restrict__ bsum_c){
  __shared__ int s[256];
  bool isC = blockIdx.x >= NB_N;
  int bid = isC ? blockIdx.x - NB_N : blockIdx.x;
  const int* cnt = isC ? cnt_c : cnt_n;
  int M = isC ? NCc : Nn;
  int tid = threadIdx.x;
  int i = bid*256 + tid;
  int v = (i < M) ? cnt[i] : 0;
  s[tid] = v; __syncthreads();
  for (int d = 1; d < 256; d <<= 1){
    int t = (tid >= d) ? s[tid-d] : 0;
    __syncthreads();
    s[tid] += t;
    __syncthreads();
  }
  if (i < M) (isC ? offs_c : offs_n)[i] = s[tid] - v;
  if (tid == 255) (isC ? bsum_c : bsum_n)[bid] = s[255];
}

__global__ __launch_bounds__(256) void k_spine(int* __restrict__ bn, int* __restrict__ bc){
  __shared__ int s[256];
  int tid = threadIdx.x;
  int v;
  if (tid < 128) v = (tid < NB_N) ? bn[tid] : 0;
  else           v = (tid-128 < NB_C) ? bc[tid-128] : 0;
  s[tid] = v; __syncthreads();
  for (int d = 1; d < 128; d <<= 1){
    int lane = tid & 127;
    int t = (lane >= d) ? s[tid-d] : 0;
    __syncthreads();
    s[tid] += t;
    __syncthreads();
  }
  if (tid < NB_N) bn[tid] = s[tid] - v;
  else if (tid >= 128 && tid-128 < NB_C) bc[tid-128] = s[tid] - v;
}

__global__ __launch_bounds__(256) void k_scan_fix(int* __restrict__ offs_n, int* __restrict__ offs_c,
                         const int* __restrict__ bn, const int* __restrict__ bc){
  int i = blockIdx.x*256 + threadIdx.x;
  if (i < Nn) offs_n[i] += bn[i >> 8];
  else if ((i -= Nn) < NCc) offs_c[i] += bc[i >> 8];
}

__global__ __launch_bounds__(256) void k_place(const int* __restrict__ ei, const int* __restrict__ cei,
                      const int* __restrict__ offs_n, const int* __restrict__ offs_c,
                      int* __restrict__ cur_n, int* __restrict__ cur_c,
                      int* __restrict__ perm_n, int* __restrict__ perm_c){
  int i = blockIdx.x*256 + threadIdx.x;
  if (i < Ee){
    int s = ei[i];
    perm_n[offs_n[s] + atomicAdd(&cur_n[s], 1)] = i;
  } else if ((i -= Ee) < ECc){
    int s = cei[i];
    perm_c[offs_c[s] + atomicAdd(&cur_c[s], 1)] = i;
  }
}

// ---------- gather edge payloads into sorted order ----------
__global__ __launch_bounds__(256) void k_gather(const int* __restrict__ ei, const int* __restrict__ cei,
                       const int* __restrict__ perm_n, const int* __restrict__ perm_c,
                       const void* __restrict__ ef, const void* __restrict__ cef,
                       const int* __restrict__ flag,
                       int2* __restrict__ sdp_n, float* __restrict__ efp_n,
                       int2* __restrict__ sdp_c, float* __restrict__ efp_c){
  int i = blockIdx.x*256 + threadIdx.x;
  int f = *flag;
  if (i < Ee*8){
    int p = i >> 3, j = i & 7;
    int e = perm_n[p];
    efp_n[i] = ldw(ef, (long)e*8 + j, f);
    if (j == 0) sdp_n[p] = make_int2(ei[e], ei[Ee + e]);
  } else if ((i -= Ee*8) < ECc*8){
    int p = i >> 3, j = i & 7;
    int e = perm_c[p];
    efp_c[i] = ldw(cef, (long)e*8 + j, f);
    if (j == 0) sdp_c[p] = make_int2(cei[e], cei[ECc + e]);
  }
}

// ---------- pack all 4 weight sets at once: set = l*2 + isClique ----------
__global__ __launch_bounds__(256) void k_wpack_all(const void* __restrict__ nn2w, const void* __restrict__ nn2b,
                          const void* __restrict__ rootw,
                          const void* __restrict__ cnn2w, const void* __restrict__ cnn2b,
                          const void* __restrict__ crootw,
                          const int* __restrict__ flag, u16* __restrict__ Wp4){
  int i = blockIdx.x*256 + threadIdx.x;
  if (i >= 4*WPSZ) return;
  int set = i / WPSZ, j = i - set*WPSZ;
  int l = set >> 1, isC = set & 1;
  const void* W2 = isC ? cnn2w : nn2w;
  const void* B2 = isC ? cnn2b : nn2b;
  const void* RW = isC ? crootw : rootw;
  int f = *flag;
  int col = j >> 5, ii = j & 31;
  float v;
  if (col < 1024)      v = ldw(W2, (long)l*32768 + ((col>>5)<<10) + (ii<<5) + (col&31), f);
  else if (col < 1056) v = ldw(B2, (long)l*1024 + (ii<<5) + (col-1024), f);
  else                 v = ldw(RW, (long)l*1024 + (ii<<5) + (col-1056), f);
  Wp4[i] = f2b(v);
}

// ---------- fused conv: MFMA T-tile into LDS + streaming prefetched edge loop ----------
__global__ __launch_bounds__(256) void k_conv_fused(const float* __restrict__ base,
                           const float* __restrict__ addagg, const int* __restrict__ adddeg, int M,
                           const int2* __restrict__ sdp, const float* __restrict__ efp,
                           const int* __restrict__ offs, int E_,
                           const void* __restrict__ w1, long w1off,
                           const void* __restrict__ b1, long b1off,
                           const u16* __restrict__ Wp,
                           const void* __restrict__ rb, long rboff,
                           const int* __restrict__ flag,
                           float* __restrict__ feat_root, float* __restrict__ agg){
  __shared__ __align__(16) u16 Ts[16*TSP];
  __shared__ float w1s[256], b1s[32];
  __shared__ float hw[4][4][34];
  int tid = threadIdx.x;
  int w = tid >> 6, lane = tid & 63;
  int quad = lane >> 4, lm = lane & 15;
  int n0 = blockIdx.x * 16;
  int f = *flag;
  w1s[tid] = ldw(w1, w1off + tid, f);
  if (tid < 32) b1s[tid] = ldw(b1, b1off + tid, f);
  // x fragment for the 16 window nodes (residual-mean folded)
  int n = n0 + lm;
  int nc = n < M ? n : M-1;
  const float* bp = base + (size_t)nc*32 + quad*8;
  s16x8 bfrag;
  if (addagg){
    int dg = adddeg[nc];
    float d = (float)(dg > 1 ? dg : 1);
    const float* ap = addagg + (size_t)nc*32 + quad*8;
    #pragma unroll
    for (int j = 0; j < 8; j++) bfrag[j] = (short)f2b(bp[j] + ap[j]/d);
  } else {
    #pragma unroll
    for (int j = 0; j < 8; j++) bfrag[j] = (short)f2b(bp[j]);
  }
  // phase 1: T tile via MFMA (wave w -> col-tiles [17w, 17w+17))
  #pragma unroll 1
  for (int ti = 0; ti < 17; ti++){
    int ct = w*17 + ti;
    int colbase = ct*16;
    s16x8 afrag = *(const s16x8*)(Wp + (size_t)(colbase + lm)*32 + quad*8);
    f32x4 acc = {0.f, 0.f, 0.f, 0.f};
    acc = __builtin_amdgcn_mfma_f32_16x16x32_bf16(afrag, bfrag, acc, 0, 0, 0);
    int cb = colbase + quad*4;   // lane holds node=lm, cols cb..cb+3
    if (ct < 66){
      u32 lo = (u32)f2b(acc[0]) | ((u32)f2b(acc[1]) << 16);
      u32 hi = (u32)f2b(acc[2]) | ((u32)f2b(acc[3]) << 16);
      *(uint2*)&Ts[lm*TSP + cb] = make_uint2(lo, hi);
    } else if (n < M){
      int o = cb - 1056;
      float4 v = make_float4(acc[0] + ldw(rb, rboff+o,   f),
                             acc[1] + ldw(rb, rboff+o+1, f),
                             acc[2] + ldw(rb, rboff+o+2, f),
                             acc[3] + ldw(rb, rboff+o+3, f));
      *(float4*)&feat_root[(size_t)n*32 + o] = v;
    }
  }
  __syncthreads();
  // phase 2: streaming edges, 4/wave-iter, register prefetch, no barriers
  int lo = offs[n0];
  int n1 = n0 + 16;
  int hi = (n1 < M) ? offs[n1] : E_;
  int eg = quad, kk = lm;
  if (kk == 0) hw[w][eg][32] = 1.0f;
  int pos = lo + w*4;
  float efv = 0.f; int sdv = 0;
  if (lane < 32){ int idx = pos*8 + lane; if (idx < hi*8) efv = efp[idx]; }
  else if (lane < 40){ int idx = pos*2 + (lane-32); if (idx < hi*2) sdv = ((const int*)sdp)[idx]; }
  for (; pos < hi; pos += 16){
    // prefetch next iteration's payload (independent addresses)
    int np = pos + 16;
    float efv_n = 0.f; int sdv_n = 0;
    if (lane < 32){ int idx = np*8 + lane; if (idx < hi*8) efv_n = efp[idx]; }
    else if (lane < 40){ int idx = np*2 + (lane-32); if (idx < hi*2) sdv_n = ((const int*)sdp)[idx]; }
    // distribute current payload
    int sn = __shfl(sdv, 32 + 2*eg);
    int dn = __shfl(sdv, 33 + 2*eg);
    bool valid = (pos + eg < hi);
    int sr = sn - n0; sr = sr < 0 ? 0 : (sr > 15 ? 15 : sr);
    // edge MLP (h) per lane
    float a0 = b1s[2*kk], a1 = b1s[2*kk+1];
    #pragma unroll
    for (int j = 0; j < 8; j++){
      float ev = __shfl(efv, eg*8 + j);
      a0 += ev * w1s[j*32 + 2*kk];
      a1 += ev * w1s[j*32 + 2*kk+1];
    }
    hw[w][eg][2*kk]   = fmaxf(a0, 0.f);
    hw[w][eg][2*kk+1] = fmaxf(a1, 0.f);
    if (valid){
      const u16* Tr = &Ts[sr*TSP];
      float m0 = 0.f, m1 = 0.f;
      #pragma unroll
      for (int k = 0; k < 33; k++){
        u32 v = *(const u32*)&Tr[k*32 + 2*kk];
        float hk = hw[w][eg][k];
        m0 += hk * bfl(v);
        m1 += hk * bfh(v);
      }
      float* ap = agg + (size_t)dn*32 + 2*kk;
      atomicAdd(ap,   m0);
      atomicAdd(ap+1, m1);
    }
    efv = efv_n; sdv = sdv_n;
  }
}

// ---------- fused: feat = relu(agg/deg + feat_root); m = feat @ w + b ----------
__global__ __launch_bounds__(256) void k_update_lin(const float* __restrict__ agg, const int* __restrict__ deg,
                           const float* __restrict__ feat_root, int M,
                           const void* __restrict__ w, long woff,
                           const void* __restrict__ b, long boff,
                           const int* __restrict__ flag,
                           float* __restrict__ feat, float* __restrict__ m_out){
  __shared__ float wsm[1024], bs[32], rows[8][33];
  int tid = threadIdx.x;
  int f = *flag;
  for (int idx = tid; idx < 1024; idx += 256) wsm[idx] = ldw(w, woff + idx, f);
  if (tid < 32) bs[tid] = ldw(b, boff + tid, f);
  int nl = tid >> 5, o = tid & 31;
  int n = blockIdx.x*8 + nl;
  if (n < M){
    int dg = deg[n];
    float d = (float)(dg > 1 ? dg : 1);
    float v = fmaxf(agg[(size_t)n*32 + o]/d + feat_root[(size_t)n*32 + o], 0.f);
    rows[nl][o] = v;
    feat[(size_t)n*32 + o] = v;
  }
  __syncthreads();
  if (n >= M) return;
  float acc = bs[o];
  #pragma unroll
  for (int j = 0; j < 32; j++) acc += rows[nl][j]*wsm[j*32+o];
  m_out[(size_t)n*32 + o] = acc;
}

__global__ __launch_bounds__(256) void k_scatter(const int* __restrict__ gidx, const int* __restrict__ sidx, int A_,
                          const float* __restrict__ m, float* __restrict__ agg){
  int i = blockIdx.x*256 + threadIdx.x;
  if (i >= A_*32) return;
  int a = i >> 5, o = i & 31;
  atomicAdd(&agg[(size_t)sidx[a]*32 + o], m[(size_t)gidx[a]*32 + o]);
}

// ---------- final store: x = xC + aggS1/deg, c = cC1 ----------
__global__ __launch_bounds__(256) void k_store(const float* __restrict__ x, const float* __restrict__ xagg,
                      const int* __restrict__ xdeg, const float* __restrict__ c,
                      void* __restrict__ out, const int* __restrict__ flag){
  int i = blockIdx.x*256 + threadIdx.x;
  int tot = Nn*32 + NCc*32;
  if (i >= tot) return;
  float v;
  if (i < Nn*32){
    int n = i >> 5;
    int dg = xdeg[n];
    float d = (float)(dg > 1 ? dg : 1);
    v = x[i] + xagg[i]/d;
  } else v = c[i - Nn*32];
  if (*flag) ((float*)out)[i] = v;
  else       ((u16*)out)[i]   = f2b(v);
}

extern "C" void kernel_launch(void* const* d_in, const int* in_sizes, int n_in,
                              void* d_out, int out_size, void* d_ws, size_t ws_size,
                              hipStream_t stream){
  const int* ei  = (const int*)d_in[1];
  const int* n2c = (const int*)d_in[4];
  const int* cei = (const int*)d_in[5];
  const void *efr = d_in[2], *cefr = d_in[6];
  const void *nn1w = d_in[7], *nn1b = d_in[8], *nn2w = d_in[9], *nn2b = d_in[10],
             *rootw = d_in[11], *rootb = d_in[12], *n2cw = d_in[13], *n2cb = d_in[14],
             *cnn1w = d_in[15], *cnn1b = d_in[16], *cnn2w = d_in[17], *cnn2b = d_in[18],
             *crootw = d_in[19], *crootb = d_in[20], *c2nw = d_in[21], *c2nb = d_in[22];

  char* ws = (char*)d_ws;
  size_t off = 0;
  auto alloc = [&](size_t bytes){ void* p = ws + off; off += (bytes + 255) & ~(size_t)255; return p; };

  // ---- zeroed region (single memset) ----
  size_t zstart = off;
  float *aggE[2], *caggS[2], *caggE[2], *aggS[2];
  for (int l = 0; l < 2; l++){
    aggE[l]  = (float*)alloc((size_t)Nn*32*4);
    caggS[l] = (float*)alloc((size_t)NCc*32*4);
    caggE[l] = (float*)alloc((size_t)NCc*32*4);
    aggS[l]  = (float*)alloc((size_t)Nn*32*4);
  }
  int* deg_nd  = (int*)alloc((size_t)Nn*4);
  int* deg_ce  = (int*)alloc((size_t)NCc*4);
  int* deg_n2c = (int*)alloc((size_t)NCc*4);
  int* deg_c2n = (int*)alloc((size_t)Nn*4);
  int* cnt_sn  = (int*)alloc((size_t)Nn*4);
  int* cnt_sc  = (int*)alloc((size_t)NCc*4);
  int* cur_n   = (int*)alloc((size_t)Nn*4);
  int* cur_c   = (int*)alloc((size_t)NCc*4);
  u32* maxbits = (u32*)alloc(256);
  int* zcnt = (int*)((char*)maxbits + 4);
  int* flag = (int*)((char*)maxbits + 8);
  int* done = (int*)((char*)maxbits + 12);
  size_t zbytes = off - zstart;

  // ---- non-zeroed ----
  float* xA  = (float*)alloc((size_t)Nn*32*4);
  float* xB  = (float*)alloc((size_t)Nn*32*4);
  float* xC  = (float*)alloc((size_t)Nn*32*4);
  float* cA  = (float*)alloc((size_t)NCc*32*4);
  float* cC0 = (float*)alloc((size_t)NCc*32*4);
  float* cC1 = (float*)alloc((size_t)NCc*32*4);
  float* m   = (float*)alloc((size_t)Nn*32*4);
  float* frn = (float*)alloc((size_t)Nn*32*4);    // feat_root (node)
  float* frc = (float*)alloc((size_t)NCc*32*4);   // feat_root (clique)
  int* offs_n = (int*)alloc((size_t)Nn*4);
  int* offs_c = (int*)alloc((size_t)NCc*4);
  int* bsum_n = (int*)alloc(512);
  int* bsum_c = (int*)alloc(512);
  int* perm_n = (int*)alloc((size_t)Ee*4);
  int* perm_c = (int*)alloc((size_t)ECc*4);
  int2* sdp_n = (int2*)alloc((size_t)Ee*8);
  int2* sdp_c = (int2*)alloc((size_t)ECc*8);
  float* efp_n = (float*)alloc((size_t)Ee*8*4);
  float* efp_c = (float*)alloc((size_t)ECc*8*4);
  u16* Wp4 = (u16*)alloc((size_t)4*WPSZ*2);

  auto nb = [](int n){ return (n + 255)/256; };

  // 1. single memset of accumulators/counters
  hipMemsetAsync(ws + zstart, 0, zbytes, stream);
  // 2. dtype detect + flag
  k_detect<<<256,256,0,stream>>>((const u16*)d_in[0], Nn*32, maxbits, zcnt, done, flag);
  // 3. features -> f32
  k_conv_all<<<nb(Nn*32 + NCc*32),256,0,stream>>>(d_in[0], d_in[3], xA, cA, flag);
  // 4. histograms + counting-sort (CSR by src) + payload gather
  k_count_all<<<nb(2*Ee + 2*ECc + 2*Aa),256,0,stream>>>(ei, cei, n2c,
      deg_nd, deg_ce, deg_n2c, deg_c2n, cnt_sn, cnt_sc);
  k_scan_block<<<NB_N+NB_C,256,0,stream>>>(cnt_sn, cnt_sc, offs_n, offs_c, bsum_n, bsum_c);
  k_spine<<<1,256,0,stream>>>(bsum_n, bsum_c);
  k_scan_fix<<<nb(Nn+NCc),256,0,stream>>>(offs_n, offs_c, bsum_n, bsum_c);
  k_place<<<nb(Ee+ECc),256,0,stream>>>(ei, cei, offs_n, offs_c, cur_n, cur_c, perm_n, perm_c);
  k_gather<<<nb(8*(Ee+ECc)),256,0,stream>>>(ei, cei, perm_n, perm_c, efr, cefr, flag,
      sdp_n, efp_n, sdp_c, efp_c);
  // 5. pack all weights
  k_wpack_all<<<nb(4*WPSZ),256,0,stream>>>(nn2w, nn2b, rootw, cnn2w, cnn2b, crootw, flag, Wp4);

  int Gn = (Nn + 15)/16, Gc = (NCc + 15)/16;

  // ---- layer 0 ----
  k_conv_fused<<<Gn,256,0,stream>>>(xA, nullptr, nullptr, Nn, sdp_n, efp_n, offs_n, Ee,
      nn1w, 0, nn1b, 0, Wp4 + 0*WPSZ, rootb, 0, flag, frn, aggE[0]);
  k_update_lin<<<(Nn+7)/8,256,0,stream>>>(aggE[0], deg_nd, frn, Nn, n2cw, 0, n2cb, 0, flag, xB, m);
  k_scatter<<<nb(Aa*32),256,0,stream>>>(n2c, n2c+Aa, Aa, m, caggS[0]);
  k_conv_fused<<<Gc,256,0,stream>>>(cA, caggS[0], deg_n2c, NCc, sdp_c, efp_c, offs_c, ECc,
      cnn1w, 0, cnn1b, 0, Wp4 + 1*WPSZ, crootb, 0, flag, frc, caggE[0]);
  k_update_lin<<<(NCc+7)/8,256,0,stream>>>(caggE[0], deg_ce, frc, NCc, c2nw, 0, c2nb, 0, flag, cC0, m);
  k_scatter<<<nb(Aa*32),256,0,stream>>>(n2c+Aa, n2c, Aa, m, aggS[0]);
  // ---- layer 1 ----
  k_conv_fused<<<Gn,256,0,stream>>>(xB, aggS[0], deg_c2n, Nn, sdp_n, efp_n, offs_n, Ee,
      nn1w, 256, nn1b, 32, Wp4 + 2*WPSZ, rootb, 32, flag, frn, aggE[1]);
  k_update_lin<<<(Nn+7)/8,256,0,stream>>>(aggE[1], deg_nd, frn, Nn, n2cw, 1024, n2cb, 32, flag, xC, m);
  k_scatter<<<nb(Aa*32),256,0,stream>>>(n2c, n2c+Aa, Aa, m, caggS[1]);
  k_conv_fused<<<Gc,256,0,stream>>>(cC0, caggS[1], deg_n2c, NCc, sdp_c, efp_c, offs_c, ECc,
      cnn1w, 256, cnn1b, 32, Wp4 + 3*WPSZ, crootb, 32, flag, frc, caggE[1]);
  k_update_lin<<<(NCc+7)/8,256,0,stream>>>(caggE[1], deg_ce, frc, NCc, c2nw, 1024, c2nb, 32, flag, cC1, m);
  k_scatter<<<nb(Aa*32),256,0,stream>>>(n2c+Aa, n2c, Aa, m, aggS[1]);
  // ---- output ----
  k_store<<<nb(Nn*32 + NCc*32),256,0,stream>>>(xC, aggS[1], deg_c2n, cC1, d_out, flag);
}

// Round 9
// 347.258 us; speedup vs baseline: 1.2771x; 1.0371x over previous
//
#include <hip/hip_runtime.h>
#include <hip/hip_bf16.h>

typedef unsigned int u32;
typedef unsigned short u16;

#define DEVINL __device__ __forceinline__

constexpr int Nn  = 25000;
constexpr int Ee  = 100000;
constexpr int NCc = 8000;
constexpr int Aa  = 50000;
constexpr int ECc = 24000;
constexpr int TCOLS = 1088;     // 34 k-rows * 32 o-cols
constexpr int WPSZ  = TCOLS*32; // one packed weight set
constexpr int TSP   = 1064;     // LDS T row stride (u16)
constexpr int NB_N = (Nn + 255)/256;   // 98 scan blocks (node)
constexpr int NB_C = (NCc + 255)/256;  // 32 scan blocks (clique)

typedef float f32x4 __attribute__((ext_vector_type(4)));
typedef short s16x8 __attribute__((ext_vector_type(8)));

DEVINL float b2f(u16 u){ union{u32 i;float f;}v; v.i = ((u32)u)<<16; return v.f; }
DEVINL float bfl(u32 u){ union{u32 i;float f;}v; v.i = u<<16; return v.f; }
DEVINL float bfh(u32 u){ union{u32 i;float f;}v; v.i = u & 0xffff0000u; return v.f; }
DEVINL u16 f2b(float f){ union{float f;u32 i;}v; v.f=f; u32 i=v.i;
  return (u16)((i + 0x7fffu + ((i>>16)&1u)) >> 16); }
DEVINL float ldw(const void* p, long i, int f){
  return f ? ((const float*)p)[i] : b2f(((const u16*)p)[i]);
}

// ---------- dtype detection + flag (fused via last-block-done) ----------
__global__ __launch_bounds__(256) void k_detect(const u16* __restrict__ p, int n,
                        u32* __restrict__ maxbits, int* __restrict__ zcnt,
                        int* __restrict__ done, int* __restrict__ flag){
  int i0 = blockIdx.x*256 + threadIdx.x;
  float lm = 0.f; int lz = 0;
  for (int i = i0; i < n; i += gridDim.x*256){
    u16 v = p[i];
    if (v == 0) lz++;
    lm = fmaxf(lm, fabsf(b2f(v)));
  }
  #pragma unroll
  for (int off = 32; off; off >>= 1){
    lm = fmaxf(lm, __shfl_down(lm, off));
    lz += __shfl_down(lz, off);
  }
  if ((threadIdx.x & 63) == 0){
    atomicMax(maxbits, __float_as_uint(lm));
    atomicAdd(zcnt, lz);
  }
  __syncthreads();
  if (threadIdx.x == 0){
    __threadfence();
    if (atomicAdd(done, 1) == gridDim.x - 1){
      float m = __uint_as_float(*maxbits);
      *flag = (m > 1e6f || *zcnt > n/4) ? 1 : 0;   // 1 => inputs are f32
    }
  }
}

// ---------- convert both feature tensors in one grid ----------
__global__ __launch_bounds__(256) void k_conv_all(const void* __restrict__ xin, const void* __restrict__ cin,
                         float* __restrict__ xA, float* __restrict__ cA, const int* __restrict__ flag){
  int i = blockIdx.x*256 + threadIdx.x;
  int f = *flag;
  if (i < Nn*32) xA[i] = ldw(xin, i, f);
  else { i -= Nn*32; if (i < NCc*32) cA[i] = ldw(cin, i, f); }
}

// ---------- all degree/count histograms in one kernel ----------
__global__ __launch_bounds__(256) void k_count_all(const int* __restrict__ ei, const int* __restrict__ cei,
                          const int* __restrict__ n2c,
                          int* __restrict__ deg_nd, int* __restrict__ deg_ce,
                          int* __restrict__ deg_n2c, int* __restrict__ deg_c2n,
                          int* __restrict__ cnt_sn, int* __restrict__ cnt_sc){
  int i = blockIdx.x*256 + threadIdx.x;
  if (i < Ee)                             atomicAdd(&deg_nd[ei[Ee + i]], 1);
  else if ((i -= Ee) < ECc)               atomicAdd(&deg_ce[cei[ECc + i]], 1);
  else if ((i -= ECc) < Aa)               atomicAdd(&deg_n2c[n2c[Aa + i]], 1);
  else if ((i -= Aa) < Aa)                atomicAdd(&deg_c2n[n2c[i]], 1);
  else if ((i -= Aa) < Ee)                atomicAdd(&cnt_sn[ei[i]], 1);
  else if ((i -= Ee) < ECc)               atomicAdd(&cnt_sc[cei[i]], 1);
}

// ---------- hierarchical scan (3 dispatches) ----------
__global__ __launch_bounds__(256) void k_scan_block(const int* __restrict__ cnt_n, const int* __restrict__ cnt_c,
                           int* __restrict__ offs_n, int* __restrict__ offs_c,
                           int* __restrict__ bsum_n, int* __restrict__ bsum_c){
  __shared__ int s[256];
  bool isC = blockIdx.x >= NB_N;
  int bid = isC ? blockIdx.x - NB_N : blockIdx.x;
  const int* cnt = isC ? cnt_c : cnt_n;
  int M = isC ? NCc : Nn;
  int tid = threadIdx.x;
  int i = bid*256 + tid;
  int v = (i < M) ? cnt[i] : 0;
  s[tid] = v; __syncthreads();
  for (int d = 1; d < 256; d <<= 1){
    int t = (tid >= d) ? s[tid-d] : 0;
    __syncthreads();
    s[tid] += t;
    __syncthreads();
  }
  if (i < M) (isC ? offs_c : offs_n)[i] = s[tid] - v;
  if (tid == 255) (isC ? bsum_c : bsum_n)[bid] = s[255];
}

__global__ __launch_bounds__(256) void k_spine(int* __restrict__ bn, int* __restrict__ bc){
  __shared__ int s[256];
  int tid = threadIdx.x;
  int v;
  if (tid < 128) v = (tid < NB_N) ? bn[tid] : 0;
  else           v = (tid-128 < NB_C) ? bc[tid-128] : 0;
  s[tid] = v; __syncthreads();
  for (int d = 1; d < 128; d <<= 1){
    int lane = tid & 127;
    int t = (lane >= d) ? s[tid-d] : 0;
    __syncthreads();
    s[tid] += t;
    __syncthreads();
  }
  if (tid < NB_N) bn[tid] = s[tid] - v;
  else if (tid >= 128 && tid-128 < NB_C) bc[tid-128] = s[tid] - v;
}

__global__ __launch_bounds__(256) void k_scan_fix(int* __restrict__ offs_n, int* __restrict__ offs_c,
                         const int* __restrict__ bn, const int* __restrict__ bc){
  int i = blockIdx.x*256 + threadIdx.x;
  if (i < Nn) offs_n[i] += bn[i >> 8];
  else if ((i -= Nn) < NCc) offs_c[i] += bc[i >> 8];
}

__global__ __launch_bounds__(256) void k_place(const int* __restrict__ ei, const int* __restrict__ cei,
                      const int* __restrict__ offs_n, const int* __restrict__ offs_c,
                      int* __restrict__ cur_n, int* __restrict__ cur_c,
                      int* __restrict__ perm_n, int* __restrict__ perm_c){
  int i = blockIdx.x*256 + threadIdx.x;
  if (i < Ee){
    int s = ei[i];
    perm_n[offs_n[s] + atomicAdd(&cur_n[s], 1)] = i;
  } else if ((i -= Ee) < ECc){
    int s = cei[i];
    perm_c[offs_c[s] + atomicAdd(&cur_c[s], 1)] = i;
  }
}

// ---------- gather edge payloads into sorted order ----------
__global__ __launch_bounds__(256) void k_gather(const int* __restrict__ ei, const int* __restrict__ cei,
                       const int* __restrict__ perm_n, const int* __restrict__ perm_c,
                       const void* __restrict__ ef, const void* __restrict__ cef,
                       const int* __restrict__ flag,
                       int2* __restrict__ sdp_n, float* __restrict__ efp_n,
                       int2* __restrict__ sdp_c, float* __restrict__ efp_c){
  int i = blockIdx.x*256 + threadIdx.x;
  int f = *flag;
  if (i < Ee*8){
    int p = i >> 3, j = i & 7;
    int e = perm_n[p];
    efp_n[i] = ldw(ef, (long)e*8 + j, f);
    if (j == 0) sdp_n[p] = make_int2(ei[e], ei[Ee + e]);
  } else if ((i -= Ee*8) < ECc*8){
    int p = i >> 3, j = i & 7;
    int e = perm_c[p];
    efp_c[i] = ldw(cef, (long)e*8 + j, f);
    if (j == 0) sdp_c[p] = make_int2(cei[e], cei[ECc + e]);
  }
}

// ---------- pack all 4 weight sets at once: set = l*2 + isClique ----------
__global__ __launch_bounds__(256) void k_wpack_all(const void* __restrict__ nn2w, const void* __restrict__ nn2b,
                          const void* __restrict__ rootw,
                          const void* __restrict__ cnn2w, const void* __restrict__ cnn2b,
                          const void* __restrict__ crootw,
                          const int* __restrict__ flag, u16* __restrict__ Wp4){
  int i = blockIdx.x*256 + threadIdx.x;
  if (i >= 4*WPSZ) return;
  int set = i / WPSZ, j = i - set*WPSZ;
  int l = set >> 1, isC = set & 1;
  const void* W2 = isC ? cnn2w : nn2w;
  const void* B2 = isC ? cnn2b : nn2b;
  const void* RW = isC ? crootw : rootw;
  int f = *flag;
  int col = j >> 5, ii = j & 31;
  float v;
  if (col < 1024)      v = ldw(W2, (long)l*32768 + ((col>>5)<<10) + (ii<<5) + (col&31), f);
  else if (col < 1056) v = ldw(B2, (long)l*1024 + (ii<<5) + (col-1024), f);
  else                 v = ldw(RW, (long)l*1024 + (ii<<5) + (col-1056), f);
  Wp4[i] = f2b(v);
}

// ---------- fused conv: 512 threads (8 waves) for full occupancy ----------
// phase 1: MFMA T tile into LDS (68 col-tiles split 9/wave)
// phase 2: streaming prefetched edge loop, 4 edges/wave-iter, packed bf16 h
__global__ __launch_bounds__(512) void k_conv_fused(const float* __restrict__ base,
                           const float* __restrict__ addagg, const int* __restrict__ adddeg, int M,
                           const int2* __restrict__ sdp, const float* __restrict__ efp,
                           const int* __restrict__ offs, int E_,
                           const void* __restrict__ w1, long w1off,
                           const void* __restrict__ b1, long b1off,
                           const u16* __restrict__ Wp,
                           const void* __restrict__ rb, long rboff,
                           const int* __restrict__ flag,
                           float* __restrict__ feat_root, float* __restrict__ agg){
  __shared__ __align__(16) u16 Ts[16*TSP];
  __shared__ float w1s[256], b1s[32];
  __shared__ u32 hws[8][4][16];
  int tid = threadIdx.x;
  int w = tid >> 6, lane = tid & 63;
  int quad = lane >> 4, lm = lane & 15;
  int n0 = blockIdx.x * 16;
  int f = *flag;
  if (tid < 256) w1s[tid] = ldw(w1, w1off + tid, f);
  else if (tid < 288) b1s[tid-256] = ldw(b1, b1off + (tid-256), f);
  // x fragment for the 16 window nodes (residual-mean folded)
  int n = n0 + lm;
  int nc = n < M ? n : M-1;
  const float* bp = base + (size_t)nc*32 + quad*8;
  s16x8 bfrag;
  if (addagg){
    int dg = adddeg[nc];
    float d = (float)(dg > 1 ? dg : 1);
    const float* ap = addagg + (size_t)nc*32 + quad*8;
    #pragma unroll
    for (int j = 0; j < 8; j++) bfrag[j] = (short)f2b(bp[j] + ap[j]/d);
  } else {
    #pragma unroll
    for (int j = 0; j < 8; j++) bfrag[j] = (short)f2b(bp[j]);
  }
  // phase 1: wave w handles col-tiles [9w, 9w+9) of 68
  #pragma unroll 1
  for (int ti = 0; ti < 9; ti++){
    int ct = w*9 + ti;
    if (ct >= 68) break;
    int colbase = ct*16;
    s16x8 afrag = *(const s16x8*)(Wp + (size_t)(colbase + lm)*32 + quad*8);
    f32x4 acc = {0.f, 0.f, 0.f, 0.f};
    acc = __builtin_amdgcn_mfma_f32_16x16x32_bf16(afrag, bfrag, acc, 0, 0, 0);
    int cb = colbase + quad*4;   // lane holds node=lm, cols cb..cb+3
    if (ct < 66){
      u32 lo = (u32)f2b(acc[0]) | ((u32)f2b(acc[1]) << 16);
      u32 hi = (u32)f2b(acc[2]) | ((u32)f2b(acc[3]) << 16);
      *(uint2*)&Ts[lm*TSP + cb] = make_uint2(lo, hi);
    } else if (n < M){
      int o = cb - 1056;
      float4 v = make_float4(acc[0] + ldw(rb, rboff+o,   f),
                             acc[1] + ldw(rb, rboff+o+1, f),
                             acc[2] + ldw(rb, rboff+o+2, f),
                             acc[3] + ldw(rb, rboff+o+3, f));
      *(float4*)&feat_root[(size_t)n*32 + o] = v;
    }
  }
  __syncthreads();
  // phase 2: streaming edges, 4/wave-iter across 8 waves, register prefetch
  int lo = offs[n0];
  int n1 = n0 + 16;
  int hi = (n1 < M) ? offs[n1] : E_;
  int eg = quad, kk = lm;
  int pos = lo + w*4;
  float efv = 0.f; int sdv = 0;
  if (lane < 32){ int idx = pos*8 + lane; if (idx < hi*8) efv = efp[idx]; }
  else if (lane < 40){ int idx = pos*2 + (lane-32); if (idx < hi*2) sdv = ((const int*)sdp)[idx]; }
  for (; pos < hi; pos += 32){
    // prefetch next iteration's payload
    int np = pos + 32;
    float efv_n = 0.f; int sdv_n = 0;
    if (lane < 32){ int idx = np*8 + lane; if (idx < hi*8) efv_n = efp[idx]; }
    else if (lane < 40){ int idx = np*2 + (lane-32); if (idx < hi*2) sdv_n = ((const int*)sdp)[idx]; }
    // distribute current payload
    int sn = __shfl(sdv, 32 + 2*eg);
    int dn = __shfl(sdv, 33 + 2*eg);
    bool valid = (pos + eg < hi);
    int sr = sn - n0; sr = sr < 0 ? 0 : (sr > 15 ? 15 : sr);
    // edge MLP (h), packed to bf16 pair
    float a0 = b1s[2*kk], a1 = b1s[2*kk+1];
    #pragma unroll
    for (int j = 0; j < 8; j++){
      float ev = __shfl(efv, eg*8 + j);
      a0 += ev * w1s[j*32 + 2*kk];
      a1 += ev * w1s[j*32 + 2*kk+1];
    }
    hws[w][eg][kk] = (u32)f2b(fmaxf(a0, 0.f)) | ((u32)f2b(fmaxf(a1, 0.f)) << 16);
    if (valid){
      const u16* Tr = &Ts[sr*TSP];
      u32 vb = *(const u32*)&Tr[1024 + 2*kk];   // b2 row (h=1)
      float m0 = bfl(vb), m1 = bfh(vb);
      #pragma unroll
      for (int kq = 0; kq < 16; kq++){
        u32 hp = hws[w][eg][kq];
        float h0 = bfl(hp), h1 = bfh(hp);
        u32 v0 = *(const u32*)&Tr[(2*kq)*32 + 2*kk];
        u32 v1 = *(const u32*)&Tr[(2*kq+1)*32 + 2*kk];
        m0 += h0*bfl(v0) + h1*bfl(v1);
        m1 += h0*bfh(v0) + h1*bfh(v1);
      }
      float* ap = agg + (size_t)dn*32 + 2*kk;
      atomicAdd(ap,   m0);
      atomicAdd(ap+1, m1);
    }
    efv = efv_n; sdv = sdv_n;
  }
}

// ---------- fused: feat = relu(agg/deg + feat_root); m = feat @ w + b ----------
__global__ __launch_bounds__(256) void k_update_lin(const float* __restrict__ agg, const int* __restrict__ deg,
                           const float* __restrict__ feat_root, int M,
                           const void* __restrict__ w, long woff,
                           const void* __restrict__ b, long boff,
                           const int* __restrict__ flag,
                           float* __restrict__ feat, float* __restrict__ m_out){
  __shared__ float wsm[1024], bs[32], rows[8][33];
  int tid = threadIdx.x;
  int f = *flag;
  for (int idx = tid; idx < 1024; idx += 256) wsm[idx] = ldw(w, woff + idx, f);
  if (tid < 32) bs[tid] = ldw(b, boff + tid, f);
  int nl = tid >> 5, o = tid & 31;
  int n = blockIdx.x*8 + nl;
  if (n < M){
    int dg = deg[n];
    float d = (float)(dg > 1 ? dg : 1);
    float v = fmaxf(agg[(size_t)n*32 + o]/d + feat_root[(size_t)n*32 + o], 0.f);
    rows[nl][o] = v;
    feat[(size_t)n*32 + o] = v;
  }
  __syncthreads();
  if (n >= M) return;
  float acc = bs[o];
  #pragma unroll
  for (int j = 0; j < 32; j++) acc += rows[nl][j]*wsm[j*32+o];
  m_out[(size_t)n*32 + o] = acc;
}

__global__ __launch_bounds__(256) void k_scatter(const int* __restrict__ gidx, const int* __restrict__ sidx, int A_,
                          const float* __restrict__ m, float* __restrict__ agg){
  int i = blockIdx.x*256 + threadIdx.x;
  if (i >= A_*32) return;
  int a = i >> 5, o = i & 31;
  atomicAdd(&agg[(size_t)sidx[a]*32 + o], m[(size_t)gidx[a]*32 + o]);
}

// ---------- final store: x = xC + aggS1/deg, c = cC1 ----------
__global__ __launch_bounds__(256) void k_store(const float* __restrict__ x, const float* __restrict__ xagg,
                      const int* __restrict__ xdeg, const float* __restrict__ c,
                      void* __restrict__ out, const int* __restrict__ flag){
  int i = blockIdx.x*256 + threadIdx.x;
  int tot = Nn*32 + NCc*32;
  if (i >= tot) return;
  float v;
  if (i < Nn*32){
    int n = i >> 5;
    int dg = xdeg[n];
    float d = (float)(dg > 1 ? dg : 1);
    v = x[i] + xagg[i]/d;
  } else v = c[i - Nn*32];
  if (*flag) ((float*)out)[i] = v;
  else       ((u16*)out)[i]   = f2b(v);
}

extern "C" void kernel_launch(void* const* d_in, const int* in_sizes, int n_in,
                              void* d_out, int out_size, void* d_ws, size_t ws_size,
                              hipStream_t stream){
  const int* ei  = (const int*)d_in[1];
  const int* n2c = (const int*)d_in[4];
  const int* cei = (const int*)d_in[5];
  const void *efr = d_in[2], *cefr = d_in[6];
  const void *nn1w = d_in[7], *nn1b = d_in[8], *nn2w = d_in[9], *nn2b = d_in[10],
             *rootw = d_in[11], *rootb = d_in[12], *n2cw = d_in[13], *n2cb = d_in[14],
             *cnn1w = d_in[15], *cnn1b = d_in[16], *cnn2w = d_in[17], *cnn2b = d_in[18],
             *crootw = d_in[19], *crootb = d_in[20], *c2nw = d_in[21], *c2nb = d_in[22];

  char* ws = (char*)d_ws;
  size_t off = 0;
  auto alloc = [&](size_t bytes){ void* p = ws + off; off += (bytes + 255) & ~(size_t)255; return p; };

  // ---- zeroed region (single memset) ----
  size_t zstart = off;
  float *aggE[2], *caggS[2], *caggE[2], *aggS[2];
  for (int l = 0; l < 2; l++){
    aggE[l]  = (float*)alloc((size_t)Nn*32*4);
    caggS[l] = (float*)alloc((size_t)NCc*32*4);
    caggE[l] = (float*)alloc((size_t)NCc*32*4);
    aggS[l]  = (float*)alloc((size_t)Nn*32*4);
  }
  int* deg_nd  = (int*)alloc((size_t)Nn*4);
  int* deg_ce  = (int*)alloc((size_t)NCc*4);
  int* deg_n2c = (int*)alloc((size_t)NCc*4);
  int* deg_c2n = (int*)alloc((size_t)Nn*4);
  int* cnt_sn  = (int*)alloc((size_t)Nn*4);
  int* cnt_sc  = (int*)alloc((size_t)NCc*4);
  int* cur_n   = (int*)alloc((size_t)Nn*4);
  int* cur_c   = (int*)alloc((size_t)NCc*4);
  u32* maxbits = (u32*)alloc(256);
  int* zcnt = (int*)((char*)maxbits + 4);
  int* flag = (int*)((char*)maxbits + 8);
  int* done = (int*)((char*)maxbits + 12);
  size_t zbytes = off - zstart;

  // ---- non-zeroed ----
  float* xA  = (float*)alloc((size_t)Nn*32*4);
  float* xB  = (float*)alloc((size_t)Nn*32*4);
  float* xC  = (float*)alloc((size_t)Nn*32*4);
  float* cA  = (float*)alloc((size_t)NCc*32*4);
  float* cC0 = (float*)alloc((size_t)NCc*32*4);
  float* cC1 = (float*)alloc((size_t)NCc*32*4);
  float* m   = (float*)alloc((size_t)Nn*32*4);
  float* frn = (float*)alloc((size_t)Nn*32*4);    // feat_root (node)
  float* frc = (float*)alloc((size_t)NCc*32*4);   // feat_root (clique)
  int* offs_n = (int*)alloc((size_t)Nn*4);
  int* offs_c = (int*)alloc((size_t)NCc*4);
  int* bsum_n = (int*)alloc(512);
  int* bsum_c = (int*)alloc(512);
  int* perm_n = (int*)alloc((size_t)Ee*4);
  int* perm_c = (int*)alloc((size_t)ECc*4);
  int2* sdp_n = (int2*)alloc((size_t)Ee*8);
  int2* sdp_c = (int2*)alloc((size_t)ECc*8);
  float* efp_n = (float*)alloc((size_t)Ee*8*4);
  float* efp_c = (float*)alloc((size_t)ECc*8*4);
  u16* Wp4 = (u16*)alloc((size_t)4*WPSZ*2);

  auto nb = [](int n){ return (n + 255)/256; };

  // 1. single memset of accumulators/counters
  hipMemsetAsync(ws + zstart, 0, zbytes, stream);
  // 2. dtype detect + flag
  k_detect<<<256,256,0,stream>>>((const u16*)d_in[0], Nn*32, maxbits, zcnt, done, flag);
  // 3. features -> f32
  k_conv_all<<<nb(Nn*32 + NCc*32),256,0,stream>>>(d_in[0], d_in[3], xA, cA, flag);
  // 4. histograms + counting-sort (CSR by src) + payload gather
  k_count_all<<<nb(2*Ee + 2*ECc + 2*Aa),256,0,stream>>>(ei, cei, n2c,
      deg_nd, deg_ce, deg_n2c, deg_c2n, cnt_sn, cnt_sc);
  k_scan_block<<<NB_N+NB_C,256,0,stream>>>(cnt_sn, cnt_sc, offs_n, offs_c, bsum_n, bsum_c);
  k_spine<<<1,256,0,stream>>>(bsum_n, bsum_c);
  k_scan_fix<<<nb(Nn+NCc),256,0,stream>>>(offs_n, offs_c, bsum_n, bsum_c);
  k_place<<<nb(Ee+ECc),256,0,stream>>>(ei, cei, offs_n, offs_c, cur_n, cur_c, perm_n, perm_c);
  k_gather<<<nb(8*(Ee+ECc)),256,0,stream>>>(ei, cei, perm_n, perm_c, efr, cefr, flag,
      sdp_n, efp_n, sdp_c, efp_c);
  // 5. pack all weights
  k_wpack_all<<<nb(4*WPSZ),256,0,stream>>>(nn2w, nn2b, rootw, cnn2w, cnn2b, crootw, flag, Wp4);

  int Gn = (Nn + 15)/16, Gc = (NCc + 15)/16;

  // ---- layer 0 ----
  k_conv_fused<<<Gn,512,0,stream>>>(xA, nullptr, nullptr, Nn, sdp_n, efp_n, offs_n, Ee,
      nn1w, 0, nn1b, 0, Wp4 + 0*WPSZ, rootb, 0, flag, frn, aggE[0]);
  k_update_lin<<<(Nn+7)/8,256,0,stream>>>(aggE[0], deg_nd, frn, Nn, n2cw, 0, n2cb, 0, flag, xB, m);
  k_scatter<<<nb(Aa*32),256,0,stream>>>(n2c, n2c+Aa, Aa, m, caggS[0]);
  k_conv_fused<<<Gc,512,0,stream>>>(cA, caggS[0], deg_n2c, NCc, sdp_c, efp_c, offs_c, ECc,
      cnn1w, 0, cnn1b, 0, Wp4 + 1*WPSZ, crootb, 0, flag, frc, caggE[0]);
  k_update_lin<<<(NCc+7)/8,256,0,stream>>>(caggE[0], deg_ce, frc, NCc, c2nw, 0, c2nb, 0, flag, cC0, m);
  k_scatter<<<nb(Aa*32),256,0,stream>>>(n2c+Aa, n2c, Aa, m, aggS[0]);
  // ---- layer 1 ----
  k_conv_fused<<<Gn,512,0,stream>>>(xB, aggS[0], deg_c2n, Nn, sdp_n, efp_n, offs_n, Ee,
      nn1w, 256, nn1b, 32, Wp4 + 2*WPSZ, rootb, 32, flag, frn, aggE[1]);
  k_update_lin<<<(Nn+7)/8,256,0,stream>>>(aggE[1], deg_nd, frn, Nn, n2cw, 1024, n2cb, 32, flag, xC, m);
  k_scatter<<<nb(Aa*32),256,0,stream>>>(n2c, n2c+Aa, Aa, m, caggS[1]);
  k_conv_fused<<<Gc,512,0,stream>>>(cC0, caggS[1], deg_n2c, NCc, sdp_c, efp_c, offs_c, ECc,
      cnn1w, 256, cnn1b, 32, Wp4 + 3*WPSZ, crootb, 32, flag, frc, caggE[1]);
  k_update_lin<<<(NCc+7)/8,256,0,stream>>>(caggE[1], deg_ce, frc, NCc, c2nw, 1024, c2nb, 32, flag, cC1, m);
  k_scatter<<<nb(Aa*32),256,0,stream>>>(n2c+Aa, n2c, Aa, m, aggS[1]);
  // ---- output ----
  k_store<<<nb(Nn*32 + NCc*32),256,0,stream>>>(xC, aggS[1], deg_c2n, cC1, d_out, flag);
}